// Round 9
// baseline (90.611 us; speedup 1.0000x reference)
//
#include <hip/hip_runtime.h>

#define TIN   4096
#define FIN   128
#define NB    64
#define FOUT  128
#define TOUT  6144
// per-batch ws layout (ints): [0,TIN) seg_start, [TIN,2TIN) tgt, [2TIN,3TIN) cum_end, [3TIN] n_segs, [3TIN+1] T_total
#define SEG_STRIDE (3 * TIN + 64)

// map tables appended in ws (int offsets)
#define MAPP_OFF (SEG_STRIDE * NB)            // NB*TOUT packed ints
#define MAPW_OFF (MAPP_OFF + NB * TOUT)       // NB*TOUT float4 weights (16B aligned)
#define WS_NEED  ((size_t)(MAPW_OFF + NB * TOUT * 4) * 4)

#define TB    512            // output t per block (2 per thread)
#define SPAN  416            // staged input window (floats per f-row)
#define SPANP (SPAN + 4)     // +4 pad so the speculative +1 tap stays in-array
#define SPAN4 (SPAN / 4)
#define ZSPL  8              // f-dim split across blockIdx.z
#define FPB   (FOUT / ZSPL)  // 16 f-rows per block
#define NLD   7              // predicated f32x4 loads per thread (16 threads/row)

typedef float f32x4 __attribute__((ext_vector_type(4)));
typedef float f32x2 __attribute__((ext_vector_type(2)));

// inclusive scan within a 64-lane wave (no barriers)
__device__ __forceinline__ int wave_iscan(int v, int lane) {
#pragma unroll
    for (int d = 1; d < 64; d <<= 1) {
        int n = __shfl_up(v, d, 64);
        if (lane >= d) v += n;
    }
    return v;
}

// block-wide (256 threads = 4 waves) inclusive scan; 2 barriers total
__device__ __forceinline__ int block_scan_incl(int v, int tid, int* wsum4, int* total) {
    const int lane = tid & 63, wid = tid >> 6;
    int incl = wave_iscan(v, lane);
    if (lane == 63) wsum4[wid] = incl;
    __syncthreads();
    int woff = 0;
#pragma unroll
    for (int i = 0; i < 3; ++i) woff += (i < wid) ? wsum4[i] : 0;
    *total = wsum4[0] + wsum4[1] + wsum4[2] + wsum4[3];
    __syncthreads();
    return incl + woff;
}

__global__ __launch_bounds__(256) void seg_kernel(const int* __restrict__ mask,
                                                  int* __restrict__ ws) {
    __shared__ int seg_start_sh[TIN];  // packed: start | (voiced<<16)
    __shared__ int tgt_sh[TIN];
    __shared__ int wsum4[4];

    const int b = blockIdx.x;
    const int tid = threadIdx.x;
    const int* mrow = mask + (size_t)b * TIN;

    for (int i = tid; i < TIN; i += 256) tgt_sh[i] = 0;

    // ---- Phase A: change flags -> segment starts; voiced count ----
    const int base = tid * 16;
    int m[16];
#pragma unroll
    for (int j = 0; j < 4; ++j) {
        int4 v = ((const int4*)(mrow + base))[j];
        m[4 * j + 0] = v.x; m[4 * j + 1] = v.y; m[4 * j + 2] = v.z; m[4 * j + 3] = v.w;
    }
    const int prev = (base == 0) ? 0 : mrow[base - 1];

    int incl[16];
    int run = 0, vsum = 0;
#pragma unroll
    for (int j = 0; j < 16; ++j) {
        int pm = (j == 0) ? prev : m[j - 1];
        int c = (base + j == 0) ? 1 : ((m[j] != pm) ? 1 : 0);
        run += c;
        incl[j] = run;
        vsum += m[j];
    }
    // packed scan: high16 = segment count, low16 = voiced count (totals <= 4096, no carry)
    int tot_packed;
    int sp = block_scan_incl((run << 16) | vsum, tid, wsum4, &tot_packed);
    const int n_segs  = tot_packed >> 16;
    const int total_v = tot_packed & 0xFFFF;
    int off = (sp >> 16) - run;
#pragma unroll
    for (int j = 0; j < 16; ++j) {
        int c = (j == 0) ? incl[0] : (incl[j] - incl[j - 1]);
        if (c) seg_start_sh[off + incl[j] - 1] = (base + j) | (m[j] << 16);
    }
    __syncthreads();

    // ---- Phase B: rates (match reference f32 op order) ----
    const float len_v = (float)total_v;
    const float len_uv = (float)TIN - len_v;
    const float ratiof = (float)(0.7 / 0.3);
    const bool both = (len_v > 0.f) && (len_uv > 0.f);
    float rv;
    if (both)              rv = (float)TOUT / (len_v + len_uv / ratiof);
    else if (len_v > 0.f)  rv = (float)TOUT / fmaxf(len_v, 1.f);
    else                   rv = (float)TOUT / fmaxf(len_uv, 1.f);
    const float ruv = both ? (rv / ratiof) : rv;

    // ---- Phase C: per-segment target lengths (last takes remainder) ----
    int lsum = 0;
    for (int s = tid; s < n_segs; s += 256) {
        int v = seg_start_sh[s];
        int st = v & 0xFFFF;
        int voiced = v >> 16;
        int en = (s + 1 < n_segs) ? (seg_start_sh[s + 1] & 0xFFFF) : TIN;
        int len = en - st;
        float scale = voiced ? rv : ruv;
        int tg = (int)fmaxf(1.0f, rintf(scale * (float)len));  // rintf == round-half-even == jnp.round
        if (s != n_segs - 1) { tgt_sh[s] = tg; lsum += tg; }
    }
    int sum_others;
    block_scan_incl(lsum, tid, wsum4, &sum_others);
    if (tid == 0) tgt_sh[n_segs - 1] = max(1, TOUT - sum_others);
    __syncthreads();

    // ---- Phase D: inclusive scan of tgt -> cum_end ----
    int tincl[16];
    int trun = 0;
#pragma unroll
    for (int j = 0; j < 16; ++j) { trun += tgt_sh[base + j]; tincl[j] = trun; }
    int ttot;
    int tsincl = block_scan_incl(trun, tid, wsum4, &ttot);
    int toff = tsincl - trun;

    int* wbp = ws + (size_t)b * SEG_STRIDE;
#pragma unroll
    for (int j = 0; j < 16; ++j) {
        int i = base + j;
        if (i < n_segs) wbp[2 * TIN + i] = toff + tincl[j];
    }
    for (int i = tid; i < n_segs; i += 256) {
        wbp[i]       = seg_start_sh[i] & 0xFFFF;
        wbp[TIN + i] = tgt_sh[i];
    }
    if (tid == 0) { wbp[3 * TIN] = n_segs; wbp[3 * TIN + 1] = ttot; }
}

// binary search + tap computation on the (L2-resident) global tables — used only by map_kernel
__device__ __forceinline__ void map_concat_g(int k, const int* __restrict__ wbp, int n_segs,
                                             int& i0, int& i1, float& w) {
    const int* cum = wbp + 2 * TIN;
    int lo = 0, hi = n_segs;
    while (lo < hi) {
        int mid = (lo + hi) >> 1;
        if (cum[mid] > k) hi = mid; else lo = mid + 1;
    }
    int s = min(lo, n_segs - 1);

    int ce = cum[s];
    int tg = wbp[TIN + s];
    int cs = ce - tg;
    int st = wbp[s];
    int en = (s + 1 < n_segs) ? wbp[s + 1] : TIN;
    float L  = (float)(en - st);
    float TL = fmaxf((float)tg, 1.f);
    float src = fmaxf(((float)(k - cs) + 0.5f) * (L / TL) - 0.5f, 0.f);
    float x0 = floorf(src);
    w = src - x0;
    float x1 = fminf(x0 + 1.f, L - 1.f);
    i0 = st + (int)x0;
    i1 = st + (int)x1;
}

// precompute per-(b,t) gather maps once: packed indices + float4 weights
__global__ __launch_bounds__(256) void map_kernel(const int* __restrict__ ws,
                                                  int* __restrict__ mapP,
                                                  float* __restrict__ mapW) {
    const int b = blockIdx.y;
    const int t = blockIdx.x * 256 + threadIdx.x;
    const int* wbp = ws + (size_t)b * SEG_STRIDE;
    const int n_segs  = wbp[3 * TIN];
    const int T_total = wbp[3 * TIN + 1];
    const bool identity = (T_total == TOUT);

    int k0, k1; float lam;
    if (identity) {
        k0 = t; k1 = t; lam = 0.f;   // (t+0.5)*1.0-0.5 == t exactly in fp32
    } else {
        float sc = fmaxf(((float)t + 0.5f) * ((float)T_total / (float)TOUT) - 0.5f, 0.f);
        k0 = (int)floorf(sc);
        k1 = min(k0 + 1, T_total - 1);
        lam = sc - (float)k0;
    }
    int a0, a1, bb0, bb1; float wa, wb;
    map_concat_g(k0, wbp, n_segs, a0, a1, wa);
    if (identity) { bb0 = a0; bb1 = a1; wb = wa; }
    else          map_concat_g(k1, wbp, n_segs, bb0, bb1, wb);

    unsigned p = (unsigned)a0 | ((a1 != a0) ? (1u << 13) : 0u) | (identity ? (1u << 14) : 0u)
               | ((unsigned)bb0 << 16) | ((bb1 != bb0) ? (1u << 29) : 0u);
    mapP[(size_t)b * TOUT + t] = (int)p;
    f32x4 w = {(1.f - lam) * (1.f - wa), (1.f - lam) * wa, lam * (1.f - wb), lam * wb};
    ((f32x4*)mapW)[(size_t)b * TOUT + t] = w;
}

__global__ __launch_bounds__(256) void resample_kernel(const float* __restrict__ mel,
                                                       const int* __restrict__ mapP,
                                                       const float* __restrict__ mapW,
                                                       float* __restrict__ out) {
    __shared__ float stage[FPB * SPANP];   // 26.9 KB single buffer -> 5 blocks/CU
    __shared__ int bcast[2];

    const int b = blockIdx.y;
    const int tid = threadIdx.x;
    const int t0 = blockIdx.x * TB + 2 * tid;   // 2 consecutive t per thread
    const int fz = blockIdx.z * FPB;

    const size_t mi = (size_t)b * TOUT + t0;
    const int2 pp = *(const int2*)(mapP + mi);      // coalesced map read
    const f32x4 wv0 = ((const f32x4*)mapW)[mi];
    const f32x4 wv1 = ((const f32x4*)mapW)[mi + 1];
    const unsigned p0 = (unsigned)pp.x, p1 = (unsigned)pp.y;

    if (tid == 0) bcast[0] = (int)(p0 & 0x1FFFu);
    if (tid == 255) {
        int A1 = (int)(p1 & 0x1FFFu) + (int)((p1 >> 13) & 1u);
        int B1 = (int)((p1 >> 16) & 0x1FFFu) + (int)((p1 >> 29) & 1u);
        bcast[1] = max(A1, B1);
    }
    __syncthreads();
    const int x_lo = bcast[0] & ~3;
    const int x_hi = bcast[1];
    const int n4 = (x_hi + 1 - x_lo + 3) >> 2;
    const bool identity = (p0 >> 14) & 1u;

    int a0r0 = (int)(p0 & 0x1FFFu),         a0r1 = (int)(p1 & 0x1FFFu);
    int b0r0 = (int)((p0 >> 16) & 0x1FFFu), b0r1 = (int)((p1 >> 16) & 0x1FFFu);
    const bool sa0 = (p0 >> 13) & 1u, sb0 = (p0 >> 29) & 1u;
    const bool sa1 = (p1 >> 13) & 1u, sb1 = (p1 >> 29) & 1u;

    if (n4 <= SPAN4) {
        // ---- fast path: one burst of independent coalesced loads -> LDS -> taps ----
        a0r0 -= x_lo; a0r1 -= x_lo; b0r0 -= x_lo; b0r1 -= x_lo;
        const int row = tid >> 4;           // 16 rows x 16 threads
        const int c0  = tid & 15;

        const f32x4* gs = (const f32x4*)(mel + ((size_t)(b * FIN + fz + row)) * TIN + x_lo);
        f32x4 R[NLD];
#pragma unroll
        for (int k = 0; k < NLD; ++k) { int c = c0 + 16 * k; if (c < n4) R[k] = gs[c]; }
        f32x4* ds = (f32x4*)(stage + row * SPANP);
#pragma unroll
        for (int k = 0; k < NLD; ++k) { int c = c0 + 16 * k; if (c < n4) ds[c] = R[k]; }
        __syncthreads();

        float* ob = out + ((size_t)(b * FOUT + fz)) * TOUT + t0;
        if (identity) {
#pragma unroll
            for (int f = 0; f < FPB; ++f) {
                const float* Lp = stage + f * SPANP;
                float xa0 = Lp[a0r0], ya0 = Lp[a0r0 + 1];   // ds_read2_b32
                float xa1 = Lp[a0r1], ya1 = Lp[a0r1 + 1];
                f32x2 v;
                v.x = wv0.x * xa0 + wv0.y * (sa0 ? ya0 : xa0);
                v.y = wv1.x * xa1 + wv1.y * (sa1 ? ya1 : xa1);
                __builtin_nontemporal_store(v, (f32x2*)(ob + (size_t)f * TOUT));
            }
        } else {
#pragma unroll
            for (int f = 0; f < FPB; ++f) {
                const float* Lp = stage + f * SPANP;
                float xa0 = Lp[a0r0], ya0 = Lp[a0r0 + 1];
                float xa1 = Lp[a0r1], ya1 = Lp[a0r1 + 1];
                float xb0 = Lp[b0r0], yb0 = Lp[b0r0 + 1];
                float xb1 = Lp[b0r1], yb1 = Lp[b0r1 + 1];
                f32x2 v;
                v.x = wv0.x * xa0 + wv0.y * (sa0 ? ya0 : xa0) + wv0.z * xb0 + wv0.w * (sb0 ? yb0 : xb0);
                v.y = wv1.x * xa1 + wv1.y * (sa1 ? ya1 : xa1) + wv1.z * xb1 + wv1.w * (sb1 ? yb1 : xb1);
                __builtin_nontemporal_store(v, (f32x2*)(ob + (size_t)f * TOUT));
            }
        }
    } else {
        // ---- fallback (pathological span): direct global gathers via absolute maps ----
        const float* mb = mel + (size_t)b * FIN * TIN;
        float* ob = out + ((size_t)(b * FOUT + fz)) * TOUT + t0;
#pragma unroll 4
        for (int f = 0; f < FPB; ++f) {
            const float* r = mb + (size_t)(fz + f) * TIN;
            float v0 = wv0.x * r[a0r0] + wv0.y * r[a0r0 + (sa0 ? 1 : 0)]
                     + wv0.z * r[b0r0] + wv0.w * r[b0r0 + (sb0 ? 1 : 0)];
            float v1 = wv1.x * r[a0r1] + wv1.y * r[a0r1 + (sa1 ? 1 : 0)]
                     + wv1.z * r[b0r1] + wv1.w * r[b0r1 + (sb1 ? 1 : 0)];
            ob[(size_t)f * TOUT + 0] = v0;
            ob[(size_t)f * TOUT + 1] = v1;
        }
    }
}

// ===================== legacy (round-7) path: used only if ws_size < WS_NEED =====================
#define LFG    8
#define LZSPL  4
#define LFPB   (FOUT / LZSPL)
#define LNCH   (LFPB / LFG)

__device__ __forceinline__ void map_concat_s(int k, const unsigned short* __restrict__ cum16,
                                             const int* __restrict__ wbp, int n_segs,
                                             int& i0, int& i1, float& w) {
    int lo = 0, hi = n_segs;
    while (lo < hi) {
        int mid = (lo + hi) >> 1;
        if ((int)cum16[mid] > k) hi = mid; else lo = mid + 1;
    }
    int s = min(lo, n_segs - 1);
    int ce = (int)cum16[s];
    int tg = wbp[TIN + s];
    int cs = ce - tg;
    int st = wbp[s];
    int en = (s + 1 < n_segs) ? wbp[s + 1] : TIN;
    float L  = (float)(en - st);
    float TL = fmaxf((float)tg, 1.f);
    float src = fmaxf(((float)(k - cs) + 0.5f) * (L / TL) - 0.5f, 0.f);
    float x0 = floorf(src);
    w = src - x0;
    float x1 = fminf(x0 + 1.f, L - 1.f);
    i0 = st + (int)x0;
    i1 = st + (int)x1;
}

__global__ __launch_bounds__(256) void resample_legacy(const float* __restrict__ mel,
                                                       const int* __restrict__ ws,
                                                       float* __restrict__ out) {
    __shared__ unsigned short cum16[TIN];
    __shared__ float stage[2][LFG * SPANP];
    __shared__ int bcast[2];

    const int b = blockIdx.y;
    const int tid = threadIdx.x;
    const int t0 = blockIdx.x * TB + tid * 2;
    const int fz = blockIdx.z * LFPB;

    const int* wbp = ws + (size_t)b * SEG_STRIDE;
    const int n_segs  = wbp[3 * TIN];
    const int T_total = wbp[3 * TIN + 1];

    for (int i = tid; i < n_segs; i += 256) cum16[i] = (unsigned short)wbp[2 * TIN + i];
    __syncthreads();

    const bool identity = (T_total == TOUT);

    int A0[2], A1[2], B0[2], B1[2];
    float W0[2], W1[2], W2[2], W3[2];
#pragma unroll
    for (int j = 0; j < 2; ++j) {
        const int t = t0 + j;
        int k0, k1; float lam;
        if (identity) { k0 = t; k1 = t; lam = 0.f; }
        else {
            float sc = fmaxf(((float)t + 0.5f) * ((float)T_total / (float)TOUT) - 0.5f, 0.f);
            k0 = (int)floorf(sc);
            k1 = min(k0 + 1, T_total - 1);
            lam = sc - (float)k0;
        }
        int a0, a1, bb0, bb1; float wa, wb;
        map_concat_s(k0, cum16, wbp, n_segs, a0, a1, wa);
        if (identity) { bb0 = a0; bb1 = a1; wb = wa; }
        else          map_concat_s(k1, cum16, wbp, n_segs, bb0, bb1, wb);
        A0[j] = a0; A1[j] = a1; B0[j] = bb0; B1[j] = bb1;
        W0[j] = (1.f - lam) * (1.f - wa);
        W1[j] = (1.f - lam) * wa;
        W2[j] = lam * (1.f - wb);
        W3[j] = lam * wb;
    }

    if (tid == 0)   bcast[0] = A0[0];
    if (tid == 255) bcast[1] = max(A1[1], B1[1]);
    __syncthreads();
    const int x_lo = bcast[0] & ~3;
    const int x_hi = bcast[1];
    const int n4 = (x_hi + 1 - x_lo + 3) >> 2;

    if (n4 <= SPAN4) {
        const int row = tid >> 5;
        const int c0  = tid & 31;
        const int a0r0 = A0[0] - x_lo, b0r0 = B0[0] - x_lo;
        const int a0r1 = A0[1] - x_lo, b0r1 = B0[1] - x_lo;
        const bool sa0 = (A1[0] == A0[0] + 1), sb0 = (B1[0] == B0[0] + 1);
        const bool sa1 = (A1[1] == A0[1] + 1), sb1 = (B1[1] == B0[1] + 1);

        f32x4 R[4];
#define L_STAGE_LOAD(ch)                                                                  \
        { const f32x4* gs = (const f32x4*)(mel + ((size_t)(b * FIN + fz + (ch) * LFG + row)) * TIN + x_lo); \
          _Pragma("unroll")                                                               \
          for (int k = 0; k < 4; ++k) { int c = c0 + 32 * k; if (c < n4) R[k] = gs[c]; } }
#define L_STAGE_WRITE(buf)                                                                \
        { f32x4* ds = (f32x4*)(stage[buf] + row * SPANP);                                 \
          _Pragma("unroll")                                                               \
          for (int k = 0; k < 4; ++k) { int c = c0 + 32 * k; if (c < n4) ds[c] = R[k]; } }

        L_STAGE_LOAD(0)
        L_STAGE_WRITE(0)
        __syncthreads();

        for (int ch = 0; ch < LNCH; ++ch) {
            const int cur = ch & 1;
            if (ch + 1 < LNCH) L_STAGE_LOAD(ch + 1)

            float* ob = out + ((size_t)(b * FOUT + fz + ch * LFG)) * TOUT + t0;
#pragma unroll
            for (int f = 0; f < LFG; ++f) {
                const float* Lp = stage[cur] + f * SPANP;
                float xa0 = Lp[a0r0], ya0 = Lp[a0r0 + 1];
                float xa1 = Lp[a0r1], ya1 = Lp[a0r1 + 1];
                float xb0 = Lp[b0r0], yb0 = Lp[b0r0 + 1];
                float xb1 = Lp[b0r1], yb1 = Lp[b0r1 + 1];
                f32x2 v;
                v.x = W0[0] * xa0 + W1[0] * (sa0 ? ya0 : xa0) + W2[0] * xb0 + W3[0] * (sb0 ? yb0 : xb0);
                v.y = W0[1] * xa1 + W1[1] * (sa1 ? ya1 : xa1) + W2[1] * xb1 + W3[1] * (sb1 ? yb1 : xb1);
                __builtin_nontemporal_store(v, (f32x2*)(ob + (size_t)f * TOUT));
            }

            if (ch + 1 < LNCH) L_STAGE_WRITE(cur ^ 1)
            __syncthreads();
        }
#undef L_STAGE_LOAD
#undef L_STAGE_WRITE
    } else {
        const float* mb = mel + (size_t)b * FIN * TIN;
        float* ob = out + ((size_t)(b * FOUT + fz)) * TOUT + t0;
#pragma unroll 4
        for (int f = 0; f < LFPB; ++f) {
            const float* r = mb + (size_t)(fz + f) * TIN;
            ob[(size_t)f * TOUT + 0] = W0[0] * r[A0[0]] + W1[0] * r[A1[0]] + W2[0] * r[B0[0]] + W3[0] * r[B1[0]];
            ob[(size_t)f * TOUT + 1] = W0[1] * r[A0[1]] + W1[1] * r[A1[1]] + W2[1] * r[B0[1]] + W3[1] * r[B1[1]];
        }
    }
}

extern "C" void kernel_launch(void* const* d_in, const int* in_sizes, int n_in,
                              void* d_out, int out_size, void* d_ws, size_t ws_size,
                              hipStream_t stream) {
    const float* mel = (const float*)d_in[0];
    const int* mask  = (const int*)d_in[1];
    float* out = (float*)d_out;
    int* ws = (int*)d_ws;

    seg_kernel<<<NB, 256, 0, stream>>>(mask, ws);

    if (ws_size >= WS_NEED) {
        int*   mapP = ws + MAPP_OFF;
        float* mapW = (float*)(ws + MAPW_OFF);
        dim3 gmap(TOUT / 256, NB);
        map_kernel<<<gmap, 256, 0, stream>>>(ws, mapP, mapW);
        dim3 grid(TOUT / TB, NB, ZSPL);
        resample_kernel<<<grid, 256, 0, stream>>>(mel, mapP, mapW, out);
    } else {
        dim3 grid(TOUT / TB, NB, LZSPL);
        resample_legacy<<<grid, 256, 0, stream>>>(mel, ws, out);
    }
}

// Round 10
// 75.333 us; speedup vs baseline: 1.2028x; 1.2028x over previous
//
#include <hip/hip_runtime.h>

#define TIN   4096
#define FIN   128
#define NB    64
#define FOUT  128
#define TOUT  6144
// per-batch ws layout (ints): [0,TIN) seg_start, [TIN,2TIN) tgt, [2TIN,3TIN) cum_end,
// [3TIN] n_segs, [3TIN+1] T_total, [3TIN+2 .. 3TIN+2+12) per-window s_lo
#define SEG_STRIDE (3 * TIN + 64)

#define TB    512            // output t per block (2 strided per thread)
#define NWIN  (TOUT / TB)    // 12 t-windows
#define SEGW  768            // staged cum window (u16); covers <=687 segments/window + margin
#define SPAN  416            // staged input window (floats per f-row)
#define SPANP (SPAN + 4)     // +4 pad so the speculative +1 tap stays in-array
#define SPAN4 (SPAN / 4)
#define FG    8              // f-rows per chunk
#define ZSPL  4              // f-dim split across blockIdx.z
#define FPB   (FOUT / ZSPL)  // 32 f-rows per block
#define NCH   (FPB / FG)     // 4 chunks per block

typedef float f32x4 __attribute__((ext_vector_type(4)));

// inclusive scan within a 64-lane wave (no barriers)
__device__ __forceinline__ int wave_iscan(int v, int lane) {
#pragma unroll
    for (int d = 1; d < 64; d <<= 1) {
        int n = __shfl_up(v, d, 64);
        if (lane >= d) v += n;
    }
    return v;
}

// block-wide (256 threads = 4 waves) inclusive scan; 2 barriers total
__device__ __forceinline__ int block_scan_incl(int v, int tid, int* wsum4, int* total) {
    const int lane = tid & 63, wid = tid >> 6;
    int incl = wave_iscan(v, lane);
    if (lane == 63) wsum4[wid] = incl;
    __syncthreads();
    int woff = 0;
#pragma unroll
    for (int i = 0; i < 3; ++i) woff += (i < wid) ? wsum4[i] : 0;
    *total = wsum4[0] + wsum4[1] + wsum4[2] + wsum4[3];
    __syncthreads();
    return incl + woff;
}

__global__ __launch_bounds__(256) void seg_kernel(const int* __restrict__ mask,
                                                  int* __restrict__ ws) {
    __shared__ int seg_start_sh[TIN];  // packed: start | (voiced<<16)
    __shared__ int tgt_sh[TIN];        // later reused to hold cum for the window searches
    __shared__ int wsum4[4];

    const int b = blockIdx.x;
    const int tid = threadIdx.x;
    const int* mrow = mask + (size_t)b * TIN;

    for (int i = tid; i < TIN; i += 256) tgt_sh[i] = 0;

    // ---- Phase A: change flags -> segment starts; voiced count ----
    const int base = tid * 16;
    int m[16];
#pragma unroll
    for (int j = 0; j < 4; ++j) {
        int4 v = ((const int4*)(mrow + base))[j];
        m[4 * j + 0] = v.x; m[4 * j + 1] = v.y; m[4 * j + 2] = v.z; m[4 * j + 3] = v.w;
    }
    const int prev = (base == 0) ? 0 : mrow[base - 1];

    int incl[16];
    int run = 0, vsum = 0;
#pragma unroll
    for (int j = 0; j < 16; ++j) {
        int pm = (j == 0) ? prev : m[j - 1];
        int c = (base + j == 0) ? 1 : ((m[j] != pm) ? 1 : 0);
        run += c;
        incl[j] = run;
        vsum += m[j];
    }
    // packed scan: high16 = segment count, low16 = voiced count (totals <= 4096, no carry)
    int tot_packed;
    int sp = block_scan_incl((run << 16) | vsum, tid, wsum4, &tot_packed);
    const int n_segs  = tot_packed >> 16;
    const int total_v = tot_packed & 0xFFFF;
    int off = (sp >> 16) - run;
#pragma unroll
    for (int j = 0; j < 16; ++j) {
        int c = (j == 0) ? incl[0] : (incl[j] - incl[j - 1]);
        if (c) seg_start_sh[off + incl[j] - 1] = (base + j) | (m[j] << 16);
    }
    __syncthreads();

    // ---- Phase B: rates (match reference f32 op order) ----
    const float len_v = (float)total_v;
    const float len_uv = (float)TIN - len_v;
    const float ratiof = (float)(0.7 / 0.3);
    const bool both = (len_v > 0.f) && (len_uv > 0.f);
    float rv;
    if (both)              rv = (float)TOUT / (len_v + len_uv / ratiof);
    else if (len_v > 0.f)  rv = (float)TOUT / fmaxf(len_v, 1.f);
    else                   rv = (float)TOUT / fmaxf(len_uv, 1.f);
    const float ruv = both ? (rv / ratiof) : rv;

    // ---- Phase C: per-segment target lengths (last takes remainder) ----
    int lsum = 0;
    for (int s = tid; s < n_segs; s += 256) {
        int v = seg_start_sh[s];
        int st = v & 0xFFFF;
        int voiced = v >> 16;
        int en = (s + 1 < n_segs) ? (seg_start_sh[s + 1] & 0xFFFF) : TIN;
        int len = en - st;
        float scale = voiced ? rv : ruv;
        int tg = (int)fmaxf(1.0f, rintf(scale * (float)len));  // rintf == round-half-even == jnp.round
        if (s != n_segs - 1) { tgt_sh[s] = tg; lsum += tg; }
    }
    int sum_others;
    block_scan_incl(lsum, tid, wsum4, &sum_others);
    if (tid == 0) tgt_sh[n_segs - 1] = max(1, TOUT - sum_others);
    __syncthreads();

    // ---- Phase D: inclusive scan of tgt -> cum_end ----
    int tincl[16];
    int trun = 0;
#pragma unroll
    for (int j = 0; j < 16; ++j) { trun += tgt_sh[base + j]; tincl[j] = trun; }
    int ttot;
    int tsincl = block_scan_incl(trun, tid, wsum4, &ttot);
    int toff = tsincl - trun;

    int* wbp = ws + (size_t)b * SEG_STRIDE;
#pragma unroll
    for (int j = 0; j < 16; ++j) {
        int i = base + j;
        if (i < n_segs) wbp[2 * TIN + i] = toff + tincl[j];
    }
    for (int i = tid; i < n_segs; i += 256) {
        wbp[i]       = seg_start_sh[i] & 0xFFFF;
        wbp[TIN + i] = tgt_sh[i];
    }
    if (tid == 0) { wbp[3 * TIN] = n_segs; wbp[3 * TIN + 1] = ttot; }

    // ---- Phase E: per-window s_lo (12 LDS binary searches; hoisted from resample) ----
    __syncthreads();                       // wbp[TIN+i] readers of tgt_sh done
#pragma unroll
    for (int j = 0; j < 16; ++j) tgt_sh[base + j] = toff + tincl[j];   // cum into LDS
    __syncthreads();
    if (tid < NWIN) {
        // k_first of window, same fp expression as resample (identity gives exactly tid*TB)
        float sc = fmaxf(((float)(tid * TB) + 0.5f) * ((float)ttot / (float)TOUT) - 0.5f, 0.f);
        int kf = max((int)floorf(sc) - 2, 0);    // -2 safety margin (covered by SEGW slack)
        int lo = 0, hi = n_segs;
        while (lo < hi) {
            int mid = (lo + hi) >> 1;
            if (tgt_sh[mid] > kf) hi = mid; else lo = mid + 1;
        }
        wbp[3 * TIN + 2 + tid] = min(lo, n_segs - 1);
    }
}

// local search on the staged cum window + tap computation
__device__ __forceinline__ void map_concat_w(int k, const unsigned short* __restrict__ cumw,
                                             int s_lo, const int* __restrict__ wbp, int n_segs,
                                             int& i0, int& i1, float& w) {
    // first idx with cumw[idx] > k (searchsorted side='right'); pads are 0xFFFF so stay in range
    int lo = 0, hi = SEGW;
    while (lo < hi) {
        int mid = (lo + hi) >> 1;
        if ((int)cumw[mid] > k) hi = mid; else lo = mid + 1;
    }
    int ce;
    int s;
    if (lo < SEGW) { s = min(s_lo + lo, n_segs - 1); ce = (int)cumw[lo]; }
    else           { s = n_segs - 1; ce = wbp[2 * TIN + s]; }  // never-taken guard

    int tg = wbp[TIN + s];
    int cs = ce - tg;
    int st = wbp[s];
    int en = (s + 1 < n_segs) ? wbp[s + 1] : TIN;
    float L  = (float)(en - st);
    float TL = fmaxf((float)tg, 1.f);
    float src = fmaxf(((float)(k - cs) + 0.5f) * (L / TL) - 0.5f, 0.f);
    float x0 = floorf(src);
    w = src - x0;
    float x1 = fminf(x0 + 1.f, L - 1.f);
    i0 = st + (int)x0;
    i1 = st + (int)x1;
}

__global__ __launch_bounds__(256) void resample_kernel(const float* __restrict__ mel,
                                                       const int* __restrict__ ws,
                                                       float* __restrict__ out) {
    __shared__ unsigned short cumw[SEGW];       // 1.5 KB cum window
    __shared__ float stage[2][FG * SPANP];      // 2 x ~13.4 KB (padded rows) -> 5 blocks/CU
    __shared__ int bcast[2];

    const int b = blockIdx.y;
    const int tid = threadIdx.x;
    const int tbase = blockIdx.x * TB;          // thread handles t = tbase+tid and +256 (strided)
    const int fz = blockIdx.z * FPB;            // this block's f-range start

    const int* wbp = ws + (size_t)b * SEG_STRIDE;
    const int n_segs  = wbp[3 * TIN];
    const int T_total = wbp[3 * TIN + 1];
    const int s_lo    = wbp[3 * TIN + 2 + blockIdx.x];

    for (int i = tid; i < SEGW; i += 256) {
        int s = s_lo + i;
        cumw[i] = (s < n_segs) ? (unsigned short)wbp[2 * TIN + s] : (unsigned short)0xFFFF;
    }
    __syncthreads();

    const bool identity = (T_total == TOUT);  // per-batch uniform -> no divergence

    int A0[2], A1[2], B0[2], B1[2];
    float W0[2], W1[2], W2[2], W3[2];
#pragma unroll
    for (int j = 0; j < 2; ++j) {
        const int t = tbase + tid + j * 256;    // strided pair: halves per-instr LDS lane stride
        int k0, k1; float lam;
        if (identity) {
            // sc = (t+0.5)*1.0 - 0.5 == t exactly in fp32 -> lam == 0
            k0 = t; k1 = t; lam = 0.f;
        } else {
            float sc = fmaxf(((float)t + 0.5f) * ((float)T_total / (float)TOUT) - 0.5f, 0.f);
            k0 = (int)floorf(sc);
            k1 = min(k0 + 1, T_total - 1);
            lam = sc - (float)k0;
        }
        int a0, a1, bb0, bb1; float wa, wb;
        map_concat_w(k0, cumw, s_lo, wbp, n_segs, a0, a1, wa);
        if (identity) { bb0 = a0; bb1 = a1; wb = wa; }
        else          map_concat_w(k1, cumw, s_lo, wbp, n_segs, bb0, bb1, wb);
        A0[j] = a0; A1[j] = a1; B0[j] = bb0; B1[j] = bb1;
        W0[j] = (1.f - lam) * (1.f - wa);
        W1[j] = (1.f - lam) * wa;
        W2[j] = lam * (1.f - wb);
        W3[j] = lam * wb;
    }

    // block input window: map is monotone in t; extremes at (tid=0,j=0) and (tid=255,j=1)
    if (tid == 0)   bcast[0] = A0[0];
    if (tid == 255) bcast[1] = max(A1[1], B1[1]);
    __syncthreads();
    const int x_lo = bcast[0] & ~3;             // align for float4 staging
    const int x_hi = bcast[1];
    const int n4 = (x_hi + 1 - x_lo + 3) >> 2;  // float4s per f-row

    if (n4 <= SPAN4) {
        // ---- fast path: reg-staged double-buffered LDS window ----
        const int row = tid >> 5;               // 8 rows x 32 threads
        const int c0  = tid & 31;
        const int a0r0 = A0[0] - x_lo, b0r0 = B0[0] - x_lo;
        const int a0r1 = A0[1] - x_lo, b0r1 = B0[1] - x_lo;
        // a1 is provably a0 or a0+1 (clamp stays inside the segment):
        // read the adjacent pair with one ds_read2 and select the clamped case away.
        const bool sa0 = (A1[0] == A0[0] + 1), sb0 = (B1[0] == B0[0] + 1);
        const bool sa1 = (A1[1] == A0[1] + 1), sb1 = (B1[1] == B0[1] + 1);

        f32x4 R[4];
#define STAGE_LOAD(ch)                                                                    \
        { const f32x4* gs = (const f32x4*)(mel + ((size_t)(b * FIN + fz + (ch) * FG + row)) * TIN + x_lo); \
          _Pragma("unroll")                                                               \
          for (int k = 0; k < 4; ++k) { int c = c0 + 32 * k; if (c < n4) R[k] = gs[c]; } }
#define STAGE_WRITE(buf)                                                                  \
        { f32x4* ds = (f32x4*)(stage[buf] + row * SPANP);                                 \
          _Pragma("unroll")                                                               \
          for (int k = 0; k < 4; ++k) { int c = c0 + 32 * k; if (c < n4) ds[c] = R[k]; } }

        STAGE_LOAD(0)
        STAGE_WRITE(0)
        __syncthreads();

        for (int ch = 0; ch < NCH; ++ch) {
            const int cur = ch & 1;
            if (ch + 1 < NCH) STAGE_LOAD(ch + 1)          // issue early; waitcnt lands at STAGE_WRITE

            float* ob = out + ((size_t)(b * FOUT + fz + ch * FG)) * TOUT + tbase + tid;
            if (identity) {
#pragma unroll
                for (int f = 0; f < FG; ++f) {
                    const float* Lp = stage[cur] + f * SPANP;
                    float xa0 = Lp[a0r0], ya0 = Lp[a0r0 + 1];   // merges to ds_read2_b32
                    float xa1 = Lp[a0r1], ya1 = Lp[a0r1 + 1];
                    float vx = W0[0] * xa0 + W1[0] * (sa0 ? ya0 : xa0);
                    float vy = W0[1] * xa1 + W1[1] * (sa1 ? ya1 : xa1);
                    __builtin_nontemporal_store(vx, ob + (size_t)f * TOUT);
                    __builtin_nontemporal_store(vy, ob + (size_t)f * TOUT + 256);
                }
            } else {
#pragma unroll
                for (int f = 0; f < FG; ++f) {
                    const float* Lp = stage[cur] + f * SPANP;
                    float xa0 = Lp[a0r0], ya0 = Lp[a0r0 + 1];
                    float xa1 = Lp[a0r1], ya1 = Lp[a0r1 + 1];
                    float xb0 = Lp[b0r0], yb0 = Lp[b0r0 + 1];
                    float xb1 = Lp[b0r1], yb1 = Lp[b0r1 + 1];
                    float vx = W0[0] * xa0 + W1[0] * (sa0 ? ya0 : xa0) + W2[0] * xb0 + W3[0] * (sb0 ? yb0 : xb0);
                    float vy = W0[1] * xa1 + W1[1] * (sa1 ? ya1 : xa1) + W2[1] * xb1 + W3[1] * (sb1 ? yb1 : xb1);
                    __builtin_nontemporal_store(vx, ob + (size_t)f * TOUT);
                    __builtin_nontemporal_store(vy, ob + (size_t)f * TOUT + 256);
                }
            }

            if (ch + 1 < NCH) STAGE_WRITE(cur ^ 1)        // write other half; readers of cur already done
            __syncthreads();
        }
#undef STAGE_LOAD
#undef STAGE_WRITE
    } else {
        // ---- fallback (pathological span): direct global gathers ----
        const float* mb = mel + (size_t)b * FIN * TIN;
        float* ob = out + ((size_t)(b * FOUT + fz)) * TOUT + tbase + tid;
#pragma unroll 4
        for (int f = 0; f < FPB; ++f) {
            const float* r = mb + (size_t)(fz + f) * TIN;
            ob[(size_t)f * TOUT]       = W0[0] * r[A0[0]] + W1[0] * r[A1[0]] + W2[0] * r[B0[0]] + W3[0] * r[B1[0]];
            ob[(size_t)f * TOUT + 256] = W0[1] * r[A0[1]] + W1[1] * r[A1[1]] + W2[1] * r[B0[1]] + W3[1] * r[B1[1]];
        }
    }
}

extern "C" void kernel_launch(void* const* d_in, const int* in_sizes, int n_in,
                              void* d_out, int out_size, void* d_ws, size_t ws_size,
                              hipStream_t stream) {
    const float* mel = (const float*)d_in[0];
    const int* mask  = (const int*)d_in[1];
    float* out = (float*)d_out;
    int* ws = (int*)d_ws;

    seg_kernel<<<NB, 256, 0, stream>>>(mask, ws);

    dim3 grid(TOUT / TB, NB, ZSPL);
    resample_kernel<<<grid, 256, 0, stream>>>(mel, ws, out);
}

// Round 11
// 71.688 us; speedup vs baseline: 1.2640x; 1.0508x over previous
//
#include <hip/hip_runtime.h>

#define TIN   4096
#define FIN   128
#define NB    64
#define FOUT  128
#define TOUT  6144
// per-batch ws layout (ints): [0,TIN) seg_start, [TIN,2TIN) tgt, [2TIN,3TIN) cum_end,
// [3TIN] n_segs, [3TIN+1] T_total, [3TIN+2 .. 3TIN+2+NWIN) per-window s_lo
#define SEG_STRIDE (3 * TIN + 64)

#define TB    256            // output t per block (1 per thread)
#define NWIN  (TOUT / TB)    // 24 t-windows
#define SEGW  384            // staged cum window (u16); covers <=~275 segments/window + margin
#define SPAN  256            // staged input window (floats per f-row); expected ~171
#define SPANP (SPAN + 4)     // +4 pad so the speculative +1 tap stays in-array
#define SPAN4 (SPAN / 4)
#define FG    8              // f-rows per chunk
#define ZSPL  4              // f-dim split across blockIdx.z
#define FPB   (FOUT / ZSPL)  // 32 f-rows per block
#define NCH   (FPB / FG)     // 4 chunks per block

typedef float f32x4 __attribute__((ext_vector_type(4)));

// inclusive scan within a 64-lane wave (no barriers)
__device__ __forceinline__ int wave_iscan(int v, int lane) {
#pragma unroll
    for (int d = 1; d < 64; d <<= 1) {
        int n = __shfl_up(v, d, 64);
        if (lane >= d) v += n;
    }
    return v;
}

// block-wide (256 threads = 4 waves) inclusive scan; 2 barriers total
__device__ __forceinline__ int block_scan_incl(int v, int tid, int* wsum4, int* total) {
    const int lane = tid & 63, wid = tid >> 6;
    int incl = wave_iscan(v, lane);
    if (lane == 63) wsum4[wid] = incl;
    __syncthreads();
    int woff = 0;
#pragma unroll
    for (int i = 0; i < 3; ++i) woff += (i < wid) ? wsum4[i] : 0;
    *total = wsum4[0] + wsum4[1] + wsum4[2] + wsum4[3];
    __syncthreads();
    return incl + woff;
}

__global__ __launch_bounds__(256) void seg_kernel(const int* __restrict__ mask,
                                                  int* __restrict__ ws) {
    __shared__ int seg_start_sh[TIN];  // packed: start | (voiced<<16)
    __shared__ int tgt_sh[TIN];        // later reused to hold cum for the window searches
    __shared__ int wsum4[4];

    const int b = blockIdx.x;
    const int tid = threadIdx.x;
    const int* mrow = mask + (size_t)b * TIN;

    for (int i = tid; i < TIN; i += 256) tgt_sh[i] = 0;

    // ---- Phase A: change flags -> segment starts; voiced count ----
    const int base = tid * 16;
    int m[16];
#pragma unroll
    for (int j = 0; j < 4; ++j) {
        int4 v = ((const int4*)(mrow + base))[j];
        m[4 * j + 0] = v.x; m[4 * j + 1] = v.y; m[4 * j + 2] = v.z; m[4 * j + 3] = v.w;
    }
    const int prev = (base == 0) ? 0 : mrow[base - 1];

    int incl[16];
    int run = 0, vsum = 0;
#pragma unroll
    for (int j = 0; j < 16; ++j) {
        int pm = (j == 0) ? prev : m[j - 1];
        int c = (base + j == 0) ? 1 : ((m[j] != pm) ? 1 : 0);
        run += c;
        incl[j] = run;
        vsum += m[j];
    }
    // packed scan: high16 = segment count, low16 = voiced count (totals <= 4096, no carry)
    int tot_packed;
    int sp = block_scan_incl((run << 16) | vsum, tid, wsum4, &tot_packed);
    const int n_segs  = tot_packed >> 16;
    const int total_v = tot_packed & 0xFFFF;
    int off = (sp >> 16) - run;
#pragma unroll
    for (int j = 0; j < 16; ++j) {
        int c = (j == 0) ? incl[0] : (incl[j] - incl[j - 1]);
        if (c) seg_start_sh[off + incl[j] - 1] = (base + j) | (m[j] << 16);
    }
    __syncthreads();

    // ---- Phase B: rates (match reference f32 op order) ----
    const float len_v = (float)total_v;
    const float len_uv = (float)TIN - len_v;
    const float ratiof = (float)(0.7 / 0.3);
    const bool both = (len_v > 0.f) && (len_uv > 0.f);
    float rv;
    if (both)              rv = (float)TOUT / (len_v + len_uv / ratiof);
    else if (len_v > 0.f)  rv = (float)TOUT / fmaxf(len_v, 1.f);
    else                   rv = (float)TOUT / fmaxf(len_uv, 1.f);
    const float ruv = both ? (rv / ratiof) : rv;

    // ---- Phase C: per-segment target lengths (last takes remainder) ----
    int lsum = 0;
    for (int s = tid; s < n_segs; s += 256) {
        int v = seg_start_sh[s];
        int st = v & 0xFFFF;
        int voiced = v >> 16;
        int en = (s + 1 < n_segs) ? (seg_start_sh[s + 1] & 0xFFFF) : TIN;
        int len = en - st;
        float scale = voiced ? rv : ruv;
        int tg = (int)fmaxf(1.0f, rintf(scale * (float)len));  // rintf == round-half-even == jnp.round
        if (s != n_segs - 1) { tgt_sh[s] = tg; lsum += tg; }
    }
    int sum_others;
    block_scan_incl(lsum, tid, wsum4, &sum_others);
    if (tid == 0) tgt_sh[n_segs - 1] = max(1, TOUT - sum_others);
    __syncthreads();

    // ---- Phase D: inclusive scan of tgt -> cum_end ----
    int tincl[16];
    int trun = 0;
#pragma unroll
    for (int j = 0; j < 16; ++j) { trun += tgt_sh[base + j]; tincl[j] = trun; }
    int ttot;
    int tsincl = block_scan_incl(trun, tid, wsum4, &ttot);
    int toff = tsincl - trun;

    int* wbp = ws + (size_t)b * SEG_STRIDE;
#pragma unroll
    for (int j = 0; j < 16; ++j) {
        int i = base + j;
        if (i < n_segs) wbp[2 * TIN + i] = toff + tincl[j];
    }
    for (int i = tid; i < n_segs; i += 256) {
        wbp[i]       = seg_start_sh[i] & 0xFFFF;
        wbp[TIN + i] = tgt_sh[i];
    }
    if (tid == 0) { wbp[3 * TIN] = n_segs; wbp[3 * TIN + 1] = ttot; }

    // ---- Phase E: per-window s_lo (NWIN LDS binary searches; hoisted from resample) ----
    __syncthreads();                       // wbp[TIN+i] readers of tgt_sh done
#pragma unroll
    for (int j = 0; j < 16; ++j) tgt_sh[base + j] = toff + tincl[j];   // cum into LDS
    __syncthreads();
    if (tid < NWIN) {
        // k_first of window, same fp expression as resample (identity gives exactly tid*TB)
        float sc = fmaxf(((float)(tid * TB) + 0.5f) * ((float)ttot / (float)TOUT) - 0.5f, 0.f);
        int kf = max((int)floorf(sc) - 2, 0);    // -2 safety margin (covered by SEGW slack)
        int lo = 0, hi = n_segs;
        while (lo < hi) {
            int mid = (lo + hi) >> 1;
            if (tgt_sh[mid] > kf) hi = mid; else lo = mid + 1;
        }
        wbp[3 * TIN + 2 + tid] = min(lo, n_segs - 1);
    }
}

// local search on the staged cum window + tap computation
__device__ __forceinline__ void map_concat_w(int k, const unsigned short* __restrict__ cumw,
                                             int s_lo, const int* __restrict__ wbp, int n_segs,
                                             int& i0, int& i1, float& w) {
    // first idx with cumw[idx] > k (searchsorted side='right'); pads are 0xFFFF so stay in range
    int lo = 0, hi = SEGW;
    while (lo < hi) {
        int mid = (lo + hi) >> 1;
        if ((int)cumw[mid] > k) hi = mid; else lo = mid + 1;
    }
    int ce;
    int s;
    if (lo < SEGW) { s = min(s_lo + lo, n_segs - 1); ce = (int)cumw[lo]; }
    else           { s = n_segs - 1; ce = wbp[2 * TIN + s]; }  // never-taken guard

    int tg = wbp[TIN + s];
    int cs = ce - tg;
    int st = wbp[s];
    int en = (s + 1 < n_segs) ? wbp[s + 1] : TIN;
    float L  = (float)(en - st);
    float TL = fmaxf((float)tg, 1.f);
    float src = fmaxf(((float)(k - cs) + 0.5f) * (L / TL) - 0.5f, 0.f);
    float x0 = floorf(src);
    w = src - x0;
    float x1 = fminf(x0 + 1.f, L - 1.f);
    i0 = st + (int)x0;
    i1 = st + (int)x1;
}

__global__ __launch_bounds__(256) void resample_kernel(const float* __restrict__ mel,
                                                       const int* __restrict__ ws,
                                                       float* __restrict__ out) {
    __shared__ unsigned short cumw[SEGW];       // 0.75 KB cum window
    __shared__ float stage[2][FG * SPANP];      // 2 x 8.1 KB (padded rows) -> 8 blocks/CU (wave cap)
    __shared__ int bcast[2];

    const int b = blockIdx.y;
    const int tid = threadIdx.x;
    const int tbase = blockIdx.x * TB;          // thread handles t = tbase + tid
    const int fz = blockIdx.z * FPB;            // this block's f-range start

    const int* wbp = ws + (size_t)b * SEG_STRIDE;
    const int n_segs  = wbp[3 * TIN];
    const int T_total = wbp[3 * TIN + 1];
    const int s_lo    = wbp[3 * TIN + 2 + blockIdx.x];

    for (int i = tid; i < SEGW; i += 256) {
        int s = s_lo + i;
        cumw[i] = (s < n_segs) ? (unsigned short)wbp[2 * TIN + s] : (unsigned short)0xFFFF;
    }
    __syncthreads();

    const bool identity = (T_total == TOUT);  // per-batch uniform -> no divergence

    const int t = tbase + tid;
    int k0, k1; float lam;
    if (identity) {
        // sc = (t+0.5)*1.0 - 0.5 == t exactly in fp32 -> lam == 0
        k0 = t; k1 = t; lam = 0.f;
    } else {
        float sc = fmaxf(((float)t + 0.5f) * ((float)T_total / (float)TOUT) - 0.5f, 0.f);
        k0 = (int)floorf(sc);
        k1 = min(k0 + 1, T_total - 1);
        lam = sc - (float)k0;
    }
    int A0, A1, B0, B1; float wa, wb;
    map_concat_w(k0, cumw, s_lo, wbp, n_segs, A0, A1, wa);
    if (identity) { B0 = A0; B1 = A1; wb = wa; }
    else          map_concat_w(k1, cumw, s_lo, wbp, n_segs, B0, B1, wb);
    const float W0 = (1.f - lam) * (1.f - wa);
    const float W1 = (1.f - lam) * wa;
    const float W2 = lam * (1.f - wb);
    const float W3 = lam * wb;

    // block input window: map is monotone in t; extremes at tid 0 / 255
    if (tid == 0)   bcast[0] = A0;
    if (tid == 255) bcast[1] = max(A1, B1);
    __syncthreads();
    const int x_lo = bcast[0] & ~3;             // align for float4 staging
    const int x_hi = bcast[1];
    const int n4 = (x_hi + 1 - x_lo + 3) >> 2;  // float4s per f-row

    if (n4 <= SPAN4) {
        // ---- fast path: reg-staged double-buffered LDS window ----
        const int row = tid >> 5;               // 8 rows x 32 threads
        const int c0  = tid & 31;
        const int a0r = A0 - x_lo, b0r = B0 - x_lo;
        // a1 is provably a0 or a0+1 (clamp stays inside the segment):
        // read the adjacent pair with one ds_read2 and select the clamped case away.
        const bool sa = (A1 == A0 + 1), sb = (B1 == B0 + 1);

        f32x4 R[2];
#define STAGE_LOAD(ch)                                                                    \
        { const f32x4* gs = (const f32x4*)(mel + ((size_t)(b * FIN + fz + (ch) * FG + row)) * TIN + x_lo); \
          _Pragma("unroll")                                                               \
          for (int k = 0; k < 2; ++k) { int c = c0 + 32 * k; if (c < n4) R[k] = gs[c]; } }
#define STAGE_WRITE(buf)                                                                  \
        { f32x4* ds = (f32x4*)(stage[buf] + row * SPANP);                                 \
          _Pragma("unroll")                                                               \
          for (int k = 0; k < 2; ++k) { int c = c0 + 32 * k; if (c < n4) ds[c] = R[k]; } }

        STAGE_LOAD(0)
        STAGE_WRITE(0)
        __syncthreads();

        for (int ch = 0; ch < NCH; ++ch) {
            const int cur = ch & 1;
            if (ch + 1 < NCH) STAGE_LOAD(ch + 1)          // issue early; waitcnt lands at STAGE_WRITE

            float* ob = out + ((size_t)(b * FOUT + fz + ch * FG)) * TOUT + t;
            if (identity) {
#pragma unroll
                for (int f = 0; f < FG; ++f) {
                    const float* Lp = stage[cur] + f * SPANP;
                    float xa = Lp[a0r], ya = Lp[a0r + 1];   // merges to ds_read2_b32
                    float v = W0 * xa + W1 * (sa ? ya : xa);
                    __builtin_nontemporal_store(v, ob + (size_t)f * TOUT);
                }
            } else {
#pragma unroll
                for (int f = 0; f < FG; ++f) {
                    const float* Lp = stage[cur] + f * SPANP;
                    float xa = Lp[a0r], ya = Lp[a0r + 1];
                    float xb = Lp[b0r], yb = Lp[b0r + 1];
                    float v = W0 * xa + W1 * (sa ? ya : xa) + W2 * xb + W3 * (sb ? yb : xb);
                    __builtin_nontemporal_store(v, ob + (size_t)f * TOUT);
                }
            }

            if (ch + 1 < NCH) STAGE_WRITE(cur ^ 1)        // write other half; readers of cur already done
            __syncthreads();
        }
#undef STAGE_LOAD
#undef STAGE_WRITE
    } else {
        // ---- fallback (pathological span): direct global gathers ----
        const float* mb = mel + (size_t)b * FIN * TIN;
        float* ob = out + ((size_t)(b * FOUT + fz)) * TOUT + t;
#pragma unroll 4
        for (int f = 0; f < FPB; ++f) {
            const float* r = mb + (size_t)(fz + f) * TIN;
            ob[(size_t)f * TOUT] = W0 * r[A0] + W1 * r[A1] + W2 * r[B0] + W3 * r[B1];
        }
    }
}

extern "C" void kernel_launch(void* const* d_in, const int* in_sizes, int n_in,
                              void* d_out, int out_size, void* d_ws, size_t ws_size,
                              hipStream_t stream) {
    const float* mel = (const float*)d_in[0];
    const int* mask  = (const int*)d_in[1];
    float* out = (float*)d_out;
    int* ws = (int*)d_ws;

    seg_kernel<<<NB, 256, 0, stream>>>(mask, ws);

    dim3 grid(TOUT / TB, NB, ZSPL);
    resample_kernel<<<grid, 256, 0, stream>>>(mel, ws, out);
}

// Round 12
// 71.266 us; speedup vs baseline: 1.2714x; 1.0059x over previous
//
#include <hip/hip_runtime.h>

#define TIN   4096
#define FIN   128
#define NB    64
#define FOUT  128
#define TOUT  6144
// per-batch ws layout (ints): [0,TIN) seg_start, [TIN,2TIN) tgt, [2TIN,3TIN) cum_end,
// [3TIN] n_segs, [3TIN+1] T_total, then per-window: s_lo[NWIN], x_lo[NWIN], x_hi[NWIN]
#define SEG_STRIDE (3 * TIN + 128)

#define TB    256            // output t per block (1 per thread)
#define NWIN  (TOUT / TB)    // 24 t-windows
#define SEGW  384            // staged cum window (u16); covers <=~275 segments/window + margin
#define SPAN  256            // staged input window (floats per f-row); expected ~171
#define SPANP (SPAN + 4)     // +4 pad so the speculative +1 tap stays in-array
#define SPAN4 (SPAN / 4)
#define FG    8              // f-rows per chunk
#define ZSPL  4              // f-dim split across blockIdx.z
#define FPB   (FOUT / ZSPL)  // 32 f-rows per block
#define NCH   (FPB / FG)     // 4 chunks per block

typedef float f32x4 __attribute__((ext_vector_type(4)));

// LDS-only barrier: orders ds ops across the block WITHOUT draining vmcnt
// (global NT stores / prefetch loads keep flying across it).
__device__ __forceinline__ void lds_barrier() {
    asm volatile("s_waitcnt lgkmcnt(0)" ::: "memory");
    __builtin_amdgcn_s_barrier();
    asm volatile("" ::: "memory");
}

// inclusive scan within a 64-lane wave (no barriers)
__device__ __forceinline__ int wave_iscan(int v, int lane) {
#pragma unroll
    for (int d = 1; d < 64; d <<= 1) {
        int n = __shfl_up(v, d, 64);
        if (lane >= d) v += n;
    }
    return v;
}

// block-wide (256 threads = 4 waves) inclusive scan; 2 barriers total
__device__ __forceinline__ int block_scan_incl(int v, int tid, int* wsum4, int* total) {
    const int lane = tid & 63, wid = tid >> 6;
    int incl = wave_iscan(v, lane);
    if (lane == 63) wsum4[wid] = incl;
    __syncthreads();
    int woff = 0;
#pragma unroll
    for (int i = 0; i < 3; ++i) woff += (i < wid) ? wsum4[i] : 0;
    *total = wsum4[0] + wsum4[1] + wsum4[2] + wsum4[3];
    __syncthreads();
    return incl + woff;
}

// edge map on seg_kernel's LDS tables (cum in cum_sh, starts in segst_sh)
__device__ __forceinline__ void edge_map(int k, const int* __restrict__ cum_sh,
                                         const int* __restrict__ segst_sh, int n_segs,
                                         int& i0, int& i1) {
    int lo = 0, hi = n_segs;
    while (lo < hi) {
        int mid = (lo + hi) >> 1;
        if (cum_sh[mid] > k) hi = mid; else lo = mid + 1;
    }
    int s = min(lo, n_segs - 1);
    int ce = cum_sh[s];
    int tg = ce - ((s > 0) ? cum_sh[s - 1] : 0);   // cum is inclusive scan of tgt
    int cs = ce - tg;
    int st = segst_sh[s] & 0xFFFF;
    int en = (s + 1 < n_segs) ? (segst_sh[s + 1] & 0xFFFF) : TIN;
    float L  = (float)(en - st);
    float TL = fmaxf((float)tg, 1.f);
    float src = fmaxf(((float)(k - cs) + 0.5f) * (L / TL) - 0.5f, 0.f);
    float x0 = floorf(src);
    float x1 = fminf(x0 + 1.f, L - 1.f);
    i0 = st + (int)x0;
    i1 = st + (int)x1;
}

__global__ __launch_bounds__(256) void seg_kernel(const int* __restrict__ mask,
                                                  int* __restrict__ ws) {
    __shared__ int seg_start_sh[TIN];  // packed: start | (voiced<<16)
    __shared__ int tgt_sh[TIN];        // later reused to hold cum for the window searches
    __shared__ int wsum4[4];

    const int b = blockIdx.x;
    const int tid = threadIdx.x;
    const int* mrow = mask + (size_t)b * TIN;

    for (int i = tid; i < TIN; i += 256) tgt_sh[i] = 0;

    // ---- Phase A: change flags -> segment starts; voiced count ----
    const int base = tid * 16;
    int m[16];
#pragma unroll
    for (int j = 0; j < 4; ++j) {
        int4 v = ((const int4*)(mrow + base))[j];
        m[4 * j + 0] = v.x; m[4 * j + 1] = v.y; m[4 * j + 2] = v.z; m[4 * j + 3] = v.w;
    }
    const int prev = (base == 0) ? 0 : mrow[base - 1];

    int incl[16];
    int run = 0, vsum = 0;
#pragma unroll
    for (int j = 0; j < 16; ++j) {
        int pm = (j == 0) ? prev : m[j - 1];
        int c = (base + j == 0) ? 1 : ((m[j] != pm) ? 1 : 0);
        run += c;
        incl[j] = run;
        vsum += m[j];
    }
    // packed scan: high16 = segment count, low16 = voiced count (totals <= 4096, no carry)
    int tot_packed;
    int sp = block_scan_incl((run << 16) | vsum, tid, wsum4, &tot_packed);
    const int n_segs  = tot_packed >> 16;
    const int total_v = tot_packed & 0xFFFF;
    int off = (sp >> 16) - run;
#pragma unroll
    for (int j = 0; j < 16; ++j) {
        int c = (j == 0) ? incl[0] : (incl[j] - incl[j - 1]);
        if (c) seg_start_sh[off + incl[j] - 1] = (base + j) | (m[j] << 16);
    }
    __syncthreads();

    // ---- Phase B: rates (match reference f32 op order) ----
    const float len_v = (float)total_v;
    const float len_uv = (float)TIN - len_v;
    const float ratiof = (float)(0.7 / 0.3);
    const bool both = (len_v > 0.f) && (len_uv > 0.f);
    float rv;
    if (both)              rv = (float)TOUT / (len_v + len_uv / ratiof);
    else if (len_v > 0.f)  rv = (float)TOUT / fmaxf(len_v, 1.f);
    else                   rv = (float)TOUT / fmaxf(len_uv, 1.f);
    const float ruv = both ? (rv / ratiof) : rv;

    // ---- Phase C: per-segment target lengths (last takes remainder) ----
    int lsum = 0;
    for (int s = tid; s < n_segs; s += 256) {
        int v = seg_start_sh[s];
        int st = v & 0xFFFF;
        int voiced = v >> 16;
        int en = (s + 1 < n_segs) ? (seg_start_sh[s + 1] & 0xFFFF) : TIN;
        int len = en - st;
        float scale = voiced ? rv : ruv;
        int tg = (int)fmaxf(1.0f, rintf(scale * (float)len));  // rintf == round-half-even == jnp.round
        if (s != n_segs - 1) { tgt_sh[s] = tg; lsum += tg; }
    }
    int sum_others;
    block_scan_incl(lsum, tid, wsum4, &sum_others);
    if (tid == 0) tgt_sh[n_segs - 1] = max(1, TOUT - sum_others);
    __syncthreads();

    // ---- Phase D: inclusive scan of tgt -> cum_end ----
    int tincl[16];
    int trun = 0;
#pragma unroll
    for (int j = 0; j < 16; ++j) { trun += tgt_sh[base + j]; tincl[j] = trun; }
    int ttot;
    int tsincl = block_scan_incl(trun, tid, wsum4, &ttot);
    int toff = tsincl - trun;

    int* wbp = ws + (size_t)b * SEG_STRIDE;
#pragma unroll
    for (int j = 0; j < 16; ++j) {
        int i = base + j;
        if (i < n_segs) wbp[2 * TIN + i] = toff + tincl[j];
    }
    for (int i = tid; i < n_segs; i += 256) {
        wbp[i]       = seg_start_sh[i] & 0xFFFF;
        wbp[TIN + i] = tgt_sh[i];
    }
    if (tid == 0) { wbp[3 * TIN] = n_segs; wbp[3 * TIN + 1] = ttot; }

    // ---- Phase E: per-window s_lo + x_lo/x_hi (hoisted from resample prologue) ----
    __syncthreads();                       // wbp[TIN+i] readers of tgt_sh done
#pragma unroll
    for (int j = 0; j < 16; ++j) tgt_sh[base + j] = toff + tincl[j];   // cum into LDS
    __syncthreads();

    const bool identity = (ttot == TOUT);
    if (tid < NWIN) {
        // s_lo: first segment possibly touched by the window (same fp expr as resample)
        float sc = fmaxf(((float)(tid * TB) + 0.5f) * ((float)ttot / (float)TOUT) - 0.5f, 0.f);
        int kf = max((int)floorf(sc) - 2, 0);    // -2 safety margin (covered by SEGW slack)
        int lo = 0, hi = n_segs;
        while (lo < hi) {
            int mid = (lo + hi) >> 1;
            if (tgt_sh[mid] > kf) hi = mid; else lo = mid + 1;
        }
        wbp[3 * TIN + 2 + tid] = min(lo, n_segs - 1);
    } else if (tid >= 64 && tid < 64 + NWIN) {
        // x_lo: A0 at the window's first t (aligned down for float4 staging)
        const int w = tid - 64;
        const int t = w * TB;
        int k0;
        if (identity) k0 = t;
        else {
            float sc = fmaxf(((float)t + 0.5f) * ((float)ttot / (float)TOUT) - 0.5f, 0.f);
            k0 = (int)floorf(sc);
        }
        int i0, i1;
        edge_map(k0, tgt_sh, seg_start_sh, n_segs, i0, i1);
        wbp[3 * TIN + 2 + NWIN + w] = i0 & ~3;
    } else if (tid >= 128 && tid < 128 + NWIN) {
        // x_hi: max(A1, B1) at the window's last t
        const int w = tid - 128;
        const int t = w * TB + TB - 1;
        int k0, k1;
        if (identity) { k0 = t; k1 = t; }
        else {
            float sc = fmaxf(((float)t + 0.5f) * ((float)ttot / (float)TOUT) - 0.5f, 0.f);
            k0 = (int)floorf(sc);
            k1 = min(k0 + 1, ttot - 1);
        }
        int a0, a1, b0, b1;
        edge_map(k0, tgt_sh, seg_start_sh, n_segs, a0, a1);
        if (identity) { b1 = a1; }
        else { edge_map(k1, tgt_sh, seg_start_sh, n_segs, b0, b1); }
        wbp[3 * TIN + 2 + 2 * NWIN + w] = max(a1, b1);
    }
}

// local search on the staged cum window + tap computation
__device__ __forceinline__ void map_concat_w(int k, const unsigned short* __restrict__ cumw,
                                             int s_lo, const int* __restrict__ wbp, int n_segs,
                                             int& i0, int& i1, float& w) {
    // first idx with cumw[idx] > k (searchsorted side='right'); pads are 0xFFFF so stay in range
    int lo = 0, hi = SEGW;
    while (lo < hi) {
        int mid = (lo + hi) >> 1;
        if ((int)cumw[mid] > k) hi = mid; else lo = mid + 1;
    }
    int ce;
    int s;
    if (lo < SEGW) { s = min(s_lo + lo, n_segs - 1); ce = (int)cumw[lo]; }
    else           { s = n_segs - 1; ce = wbp[2 * TIN + s]; }  // never-taken guard

    int tg = wbp[TIN + s];
    int cs = ce - tg;
    int st = wbp[s];
    int en = (s + 1 < n_segs) ? wbp[s + 1] : TIN;
    float L  = (float)(en - st);
    float TL = fmaxf((float)tg, 1.f);
    float src = fmaxf(((float)(k - cs) + 0.5f) * (L / TL) - 0.5f, 0.f);
    float x0 = floorf(src);
    w = src - x0;
    float x1 = fminf(x0 + 1.f, L - 1.f);
    i0 = st + (int)x0;
    i1 = st + (int)x1;
}

// global-table search (fallback path only)
__device__ __forceinline__ void map_concat_g(int k, const int* __restrict__ wbp, int n_segs,
                                             int& i0, int& i1, float& w) {
    const int* cum = wbp + 2 * TIN;
    int lo = 0, hi = n_segs;
    while (lo < hi) {
        int mid = (lo + hi) >> 1;
        if (cum[mid] > k) hi = mid; else lo = mid + 1;
    }
    int s = min(lo, n_segs - 1);
    int ce = cum[s];
    int tg = wbp[TIN + s];
    int cs = ce - tg;
    int st = wbp[s];
    int en = (s + 1 < n_segs) ? wbp[s + 1] : TIN;
    float L  = (float)(en - st);
    float TL = fmaxf((float)tg, 1.f);
    float src = fmaxf(((float)(k - cs) + 0.5f) * (L / TL) - 0.5f, 0.f);
    float x0 = floorf(src);
    w = src - x0;
    float x1 = fminf(x0 + 1.f, L - 1.f);
    i0 = st + (int)x0;
    i1 = st + (int)x1;
}

__global__ __launch_bounds__(256) void resample_kernel(const float* __restrict__ mel,
                                                       const int* __restrict__ ws,
                                                       float* __restrict__ out) {
    __shared__ unsigned short cumw[SEGW];       // 0.75 KB cum window
    __shared__ float stage[2][FG * SPANP];      // 2 x 8.1 KB (padded rows) -> 8 blocks/CU (wave cap)

    const int b = blockIdx.y;
    const int tid = threadIdx.x;
    const int tbase = blockIdx.x * TB;          // thread handles t = tbase + tid
    const int fz = blockIdx.z * FPB;            // this block's f-range start

    const int* wbp = ws + (size_t)b * SEG_STRIDE;
    const int n_segs  = wbp[3 * TIN];
    const int T_total = wbp[3 * TIN + 1];
    const int s_lo    = wbp[3 * TIN + 2 + blockIdx.x];
    const int x_lo    = wbp[3 * TIN + 2 + NWIN + blockIdx.x];       // pre-aligned (&~3)
    const int x_hi    = wbp[3 * TIN + 2 + 2 * NWIN + blockIdx.x];
    const int n4 = (x_hi + 1 - x_lo + 3) >> 2;  // float4s per f-row

    const bool identity = (T_total == TOUT);  // per-batch uniform -> no divergence
    const int t = tbase + tid;

    int k0, k1; float lam;
    if (identity) {
        // sc = (t+0.5)*1.0 - 0.5 == t exactly in fp32 -> lam == 0
        k0 = t; k1 = t; lam = 0.f;
    } else {
        float sc = fmaxf(((float)t + 0.5f) * ((float)T_total / (float)TOUT) - 0.5f, 0.f);
        k0 = (int)floorf(sc);
        k1 = min(k0 + 1, T_total - 1);
        lam = sc - (float)k0;
    }

    if (n4 <= SPAN4) {
        // ---- fast path ----
        const int row = tid >> 5;               // 8 rows x 32 threads
        const int c0  = tid & 31;

        // 1) issue cum-window loads FIRST (oldest in vmcnt queue) ...
        int cv0 = 0xFFFF, cv1 = 0xFFFF;
        { int s = s_lo + tid; if (s < n_segs) cv0 = wbp[2 * TIN + s]; }
        if (tid < SEGW - 256) { int s = s_lo + tid + 256; if (s < n_segs) cv1 = wbp[2 * TIN + s]; }

        // 2) ... then the first stage burst: its latency hides under the map search below
        f32x4 R[2];
#define STAGE_LOAD(ch)                                                                    \
        { const f32x4* gs = (const f32x4*)(mel + ((size_t)(b * FIN + fz + (ch) * FG + row)) * TIN + x_lo); \
          _Pragma("unroll")                                                               \
          for (int k = 0; k < 2; ++k) { int c = c0 + 32 * k; if (c < n4) R[k] = gs[c]; } }
#define STAGE_WRITE(buf)                                                                  \
        { f32x4* ds = (f32x4*)(stage[buf] + row * SPANP);                                 \
          _Pragma("unroll")                                                               \
          for (int k = 0; k < 2; ++k) { int c = c0 + 32 * k; if (c < n4) ds[c] = R[k]; } }

        STAGE_LOAD(0)

        // 3) cumw writes (in-order vmcnt wait covers only the cum loads, not the stage burst)
        cumw[tid] = (unsigned short)cv0;
        if (tid < SEGW - 256) cumw[tid + 256] = (unsigned short)cv1;
        lds_barrier();

        // 4) per-thread map search on the LDS cum window (overlaps stage-load latency)
        int A0, A1, B0, B1; float wa, wb;
        map_concat_w(k0, cumw, s_lo, wbp, n_segs, A0, A1, wa);
        if (identity) { B0 = A0; B1 = A1; wb = wa; }
        else          map_concat_w(k1, cumw, s_lo, wbp, n_segs, B0, B1, wb);
        const float W0 = (1.f - lam) * (1.f - wa);
        const float W1 = (1.f - lam) * wa;
        const float W2 = lam * (1.f - wb);
        const float W3 = lam * wb;
        const int a0r = A0 - x_lo, b0r = B0 - x_lo;
        const bool sa = (A1 == A0 + 1), sb = (B1 == B0 + 1);

        // 5) stage buffer 0, then the chunk loop (LDS-only barriers: NT stores never drained)
        STAGE_WRITE(0)
        lds_barrier();

        for (int ch = 0; ch < NCH; ++ch) {
            const int cur = ch & 1;
            if (ch + 1 < NCH) STAGE_LOAD(ch + 1)          // issue early; waitcnt lands at STAGE_WRITE

            float* ob = out + ((size_t)(b * FOUT + fz + ch * FG)) * TOUT + t;
            if (identity) {
#pragma unroll
                for (int f = 0; f < FG; ++f) {
                    const float* Lp = stage[cur] + f * SPANP;
                    float xa = Lp[a0r], ya = Lp[a0r + 1];   // merges to ds_read2_b32
                    float v = W0 * xa + W1 * (sa ? ya : xa);
                    __builtin_nontemporal_store(v, ob + (size_t)f * TOUT);
                }
            } else {
#pragma unroll
                for (int f = 0; f < FG; ++f) {
                    const float* Lp = stage[cur] + f * SPANP;
                    float xa = Lp[a0r], ya = Lp[a0r + 1];
                    float xb = Lp[b0r], yb = Lp[b0r + 1];
                    float v = W0 * xa + W1 * (sa ? ya : xa) + W2 * xb + W3 * (sb ? yb : xb);
                    __builtin_nontemporal_store(v, ob + (size_t)f * TOUT);
                }
            }

            if (ch + 1 < NCH) STAGE_WRITE(cur ^ 1)        // write other half; readers of cur already done
            lds_barrier();
        }
#undef STAGE_LOAD
#undef STAGE_WRITE
    } else {
        // ---- fallback (pathological span): direct global gathers, global-table search ----
        int A0, A1, B0, B1; float wa, wb;
        map_concat_g(k0, wbp, n_segs, A0, A1, wa);
        if (identity) { B0 = A0; B1 = A1; wb = wa; }
        else          map_concat_g(k1, wbp, n_segs, B0, B1, wb);
        const float W0 = (1.f - lam) * (1.f - wa);
        const float W1 = (1.f - lam) * wa;
        const float W2 = lam * (1.f - wb);
        const float W3 = lam * wb;

        const float* mb = mel + (size_t)b * FIN * TIN;
        float* ob = out + ((size_t)(b * FOUT + fz)) * TOUT + t;
#pragma unroll 4
        for (int f = 0; f < FPB; ++f) {
            const float* r = mb + (size_t)(fz + f) * TIN;
            ob[(size_t)f * TOUT] = W0 * r[A0] + W1 * r[A1] + W2 * r[B0] + W3 * r[B1];
        }
    }
}

extern "C" void kernel_launch(void* const* d_in, const int* in_sizes, int n_in,
                              void* d_out, int out_size, void* d_ws, size_t ws_size,
                              hipStream_t stream) {
    const float* mel = (const float*)d_in[0];
    const int* mask  = (const int*)d_in[1];
    float* out = (float*)d_out;
    int* ws = (int*)d_ws;

    seg_kernel<<<NB, 256, 0, stream>>>(mask, ws);

    dim3 grid(TOUT / TB, NB, ZSPL);
    resample_kernel<<<grid, 256, 0, stream>>>(mel, ws, out);
}